// Round 13
// baseline (204.903 us; speedup 1.0000x reference)
//
#include <hip/hip_runtime.h>
#include <math.h>

#define BB 128
#define SS 200
#define MM 50
#define DKK 64
#define DVV 128
#define FF 64
#define NROW (BB*SS)   // 25600

#define WROW 64        // w padded layout: 64 floats/row, m<50 valid, rest zero
#define NFCB (NROW/64) // 400 k_fc blocks
#define WLDS 136       // k_pre/ea LDS bf16 row stride (2-way bank alias = free)
#define CLEN 25        // scan: steps per chunk (8 chunks x 25 = 200)
#define MP 25          // scan: m-pairs per thread (50 m as 25 float2)
#define NSCB 100       // scores blocks inside k_pre (256 items each)

// workspace layout (floats)
#define W_OFF   0L
#define EA_OFF  (W_OFF + (long)NROW*WROW)        // interleaved (e,a) float2
#define R_OFF   (EA_OFF + (long)NROW*DVV*2)
#define ACC_OFF (R_OFF + (long)NROW*DVV)         // [0]=bce [1]=cnt [2]=counter bits

typedef __attribute__((ext_vector_type(8))) short bf16x8;   // 8 bf16 (4 VGPRs)
typedef __attribute__((ext_vector_type(4))) float f32x4;
typedef __attribute__((ext_vector_type(2))) float f32x2;    // -> v_pk_*_f32

__device__ __forceinline__ float rlane(float v, int l) {
    return __builtin_bit_cast(float, __builtin_amdgcn_readlane(__builtin_bit_cast(unsigned, v), l));
}
__device__ __forceinline__ short f2bf(float f) {   // RNE fp32->bf16
    unsigned u = __builtin_bit_cast(unsigned, f);
    u += 0x7fff + ((u >> 16) & 1);
    return (short)(u >> 16);
}

// ---------------- Kernel 1: fused scores + ea (independent block types) ----------------
__global__ __launch_bounds__(256) void k_pre(const int* __restrict__ q_data,
                                             const float* __restrict__ q_embed_w,
                                             const float* __restrict__ mem_key,
                                             const int* __restrict__ qa_data,
                                             const float* __restrict__ qa_embed_w,
                                             const float* __restrict__ erase_w,
                                             const float* __restrict__ erase_b,
                                             const float* __restrict__ add_w,
                                             const float* __restrict__ add_b,
                                             float* __restrict__ w_out,
                                             float* __restrict__ EA,
                                             float* __restrict__ acc) {
    __shared__ union {
        short  wl[2 * 128 * WLDS];   // ea branch: bf16 weights, 69.6 KB
        float4 mk[MM * 16];          // scores branch: mem_key, 12.8 KB
    } sh;
    int tid = threadIdx.x;
    int bid = blockIdx.x;

    if (bid < NSCB) {
        // ---------- scores branch ----------
        if (bid == 0 && tid == 0) {
            acc[0] = 0.f; acc[1] = 0.f;
            ((unsigned*)acc)[2] = 0u;
        }
        const float4* mkg = (const float4*)mem_key;
        for (int i = tid; i < MM * 16; i += 256) sh.mk[i] = mkg[i];
        __syncthreads();

        int item = bid * 256 + tid;
        int qidx = q_data[item];
        const float4* qg = (const float4*)(q_embed_w + (long)qidx * DKK);
        float4 q[16];
#pragma unroll
        for (int i = 0; i < 16; i++) q[i] = qg[i];

        float s[MM];
        float mx = -1e30f;
#pragma unroll 2
        for (int m = 0; m < MM; m++) {
            float a = 0.f;
#pragma unroll
            for (int k4 = 0; k4 < 16; k4++) {
                float4 mkv = sh.mk[m * 16 + k4];
                float4 qv = q[k4];
                a = fmaf(qv.x, mkv.x, a);
                a = fmaf(qv.y, mkv.y, a);
                a = fmaf(qv.z, mkv.z, a);
                a = fmaf(qv.w, mkv.w, a);
            }
            s[m] = a;
            mx = fmaxf(mx, a);
        }
        float sum = 0.f;
#pragma unroll
        for (int m = 0; m < MM; m++) { s[m] = expf(s[m] - mx); sum += s[m]; }
        float inv = 1.f / sum;

        float* wo = w_out + (long)item * WROW;
#pragma unroll
        for (int m = 0; m < MM; m++) wo[m] = s[m] * inv;
#pragma unroll
        for (int m = MM; m < WROW; m++) wo[m] = 0.f;
        return;
    }

    // ---------- ea branch ----------
    int r0 = (bid - NSCB) * 64;
    int lane = tid & 63;
    int wv = tid >> 6;          // wave 0..3
    int n = lane & 15;
    int quad = lane >> 4;       // 0..3

    for (int i = tid; i < 8192; i += 256) {
        int mat = i >> 12;
        int r = (i >> 5) & 127;
        int p = i & 31;
        float4 src = *(const float4*)((mat ? add_w : erase_w) + r * 128 + p * 4);
        short4 d;
        d.x = f2bf(src.x); d.y = f2bf(src.y); d.z = f2bf(src.z); d.w = f2bf(src.w);
        *(short4*)(sh.wl + (mat * 128 + r) * WLDS + p * 4) = d;
    }

    int arow = r0 + wv * 16 + n;
    int qidx = qa_data[arow];
    const float* qp = qa_embed_w + (long)qidx * DVV + quad * 8;
    bf16x8 afrag[4];
#pragma unroll
    for (int kb = 0; kb < 4; kb++) {
        float4 lo = *(const float4*)(qp + kb * 32);
        float4 hi = *(const float4*)(qp + kb * 32 + 4);
        bf16x8 f;
        f[0] = f2bf(lo.x); f[1] = f2bf(lo.y); f[2] = f2bf(lo.z); f[3] = f2bf(lo.w);
        f[4] = f2bf(hi.x); f[5] = f2bf(hi.y); f[6] = f2bf(hi.z); f[7] = f2bf(hi.w);
        afrag[kb] = f;
    }

    float eb_[8], ab_[8];
#pragma unroll
    for (int vt = 0; vt < 8; vt++) {
        eb_[vt] = erase_b[vt * 16 + n];
        ab_[vt] = add_b[vt * 16 + n];
    }
    __syncthreads();

    int rowbase = r0 + wv * 16 + quad * 4;
#pragma unroll 2
    for (int vt = 0; vt < 8; vt++) {
        int vrow = vt * 16 + n;
        f32x4 ae = {0.f, 0.f, 0.f, 0.f};
        f32x4 aa = {0.f, 0.f, 0.f, 0.f};
#pragma unroll
        for (int kb = 0; kb < 4; kb++) {
            bf16x8 be = *(const bf16x8*)(sh.wl + vrow * WLDS + kb * 32 + quad * 8);
            bf16x8 ba = *(const bf16x8*)(sh.wl + (128 + vrow) * WLDS + kb * 32 + quad * 8);
            ae = __builtin_amdgcn_mfma_f32_16x16x32_bf16(afrag[kb], be, ae, 0, 0, 0);
            aa = __builtin_amdgcn_mfma_f32_16x16x32_bf16(afrag[kb], ba, aa, 0, 0, 0);
        }
        int v = vt * 16 + n;
        float eb = eb_[vt], ab = ab_[vt];
#pragma unroll
        for (int r = 0; r < 4; r++) {
            float ev = 1.f / (1.f + __expf(-(ae[r] + eb)));
            float av = 2.f / (1.f + __expf(-2.f * (aa[r] + ab))) - 1.f;
            float2 o; o.x = ev; o.y = av;
            *(float2*)(EA + (((long)(rowbase + r)) * DVV + v) * 2) = o;
        }
    }
}

// ---------------- Kernel 2: chunked affine scan — depth-2 software pipeline ----------------
// Block = (b, v_half): 8 waves = 8 chunks of 25 steps; lane = v; 50 m in-thread as
// 25 float2 (v_pk ops). Loads (w, EA) prefetched TWO steps ahead -> covers L3 latency.
__global__ __launch_bounds__(512, 2) void k_scan(const float* __restrict__ w_pad,
                                                 const float* __restrict__ EA,
                                                 const float* __restrict__ init_mv,
                                                 float* __restrict__ R) {
    __shared__ float Sb[MM * 64];      // 12.8 KB boundary state
    int b   = blockIdx.x >> 1;
    int vh  = blockIdx.x & 1;
    int tid = threadIdx.x;
    int lane  = tid & 63;
    int chunk = tid >> 6;              // wave id = chunk (0..7)
    int v  = vh * 64 + lane;
    int t0 = chunk * CLEN;

    const float* wbase = w_pad + ((long)b * SS + t0) * WROW;
    const float* eab   = EA + (((long)b * SS + t0) * DVV + v) * 2;
    float*       Rb    = R + ((long)b * SS + t0) * DVV + v;

    const f32x2 one = {1.f, 1.f};

    // ---- pass 1: compose the chunk's affine map per m-pair ----
    f32x2 A2[MP], B2[MP];
#pragma unroll
    for (int j = 0; j < MP; j++) { A2[j] = one; B2[j] = (f32x2){0.f, 0.f}; }

    float  wq[2];
    float2 eaq[2];
    wq[0]  = wbase[lane];
    eaq[0] = *(const float2*)eab;
    wq[1]  = wbase[WROW + lane];
    eaq[1] = *(const float2*)(eab + (long)DVV * 2);
#pragma unroll 1
    for (int t = 0; t < CLEN; t++) {
        int tp = (t + 2 < CLEN) ? t + 2 : CLEN - 1;
        float  w_n  = wbase[tp * WROW + lane];
        float2 ea_n = *(const float2*)(eab + (long)tp * DVV * 2);
        int sl = t & 1;
        float  w_cur  = wq[sl];
        float2 ea_cur = eaq[sl];
        f32x2 e2 = {ea_cur.x, ea_cur.x};
        f32x2 a2 = {ea_cur.y, ea_cur.y};
#pragma unroll
        for (int j = 0; j < MP; j++) {
            f32x2 w2 = {rlane(w_cur, 2 * j), rlane(w_cur, 2 * j + 1)};
            f32x2 alpha = one - w2 * e2;
            A2[j] = A2[j] * alpha;
            B2[j] = alpha * B2[j] + w2 * a2;
        }
        wq[sl] = w_n; eaq[sl] = ea_n;
    }

    // ---- combine: sequential over chunks through LDS ----
    f32x2 Mv[MP];
    if (chunk == 0) {
#pragma unroll
        for (int j = 0; j < MP; j++) {
            Mv[j].x = init_mv[(2 * j) * DVV + v];
            Mv[j].y = init_mv[(2 * j + 1) * DVV + v];
        }
#pragma unroll
        for (int j = 0; j < MP; j++) {
            f32x2 nb = A2[j] * Mv[j] + B2[j];
            Sb[(2 * j) * 64 + lane] = nb.x;
            Sb[(2 * j + 1) * 64 + lane] = nb.y;
        }
    }
    __syncthreads();
    for (int c = 1; c < 8; c++) {
        if (chunk == c) {
#pragma unroll
            for (int j = 0; j < MP; j++) {
                Mv[j].x = Sb[(2 * j) * 64 + lane];
                Mv[j].y = Sb[(2 * j + 1) * 64 + lane];
            }
            if (c < 7) {
#pragma unroll
                for (int j = 0; j < MP; j++) {
                    f32x2 nb = A2[j] * Mv[j] + B2[j];
                    Sb[(2 * j) * 64 + lane] = nb.x;
                    Sb[(2 * j + 1) * 64 + lane] = nb.y;
                }
            }
        }
        __syncthreads();
    }

    // ---- pass 2: replay chunk, emitting reads (pre-update Mv) ----
    wq[0]  = wbase[lane];
    eaq[0] = *(const float2*)eab;
    wq[1]  = wbase[WROW + lane];
    eaq[1] = *(const float2*)(eab + (long)DVV * 2);
#pragma unroll 1
    for (int t = 0; t < CLEN; t++) {
        int tp = (t + 2 < CLEN) ? t + 2 : CLEN - 1;
        float  w_n  = wbase[tp * WROW + lane];
        float2 ea_n = *(const float2*)(eab + (long)tp * DVV * 2);
        int sl = t & 1;
        float  w_cur  = wq[sl];
        float2 ea_cur = eaq[sl];
        f32x2 e2 = {ea_cur.x, ea_cur.x};
        f32x2 a2 = {ea_cur.y, ea_cur.y};
        f32x2 rd2 = {0.f, 0.f};
#pragma unroll
        for (int j = 0; j < MP; j++) {
            f32x2 w2 = {rlane(w_cur, 2 * j), rlane(w_cur, 2 * j + 1)};
            rd2 = rd2 + w2 * Mv[j];               // read uses PRE-update Mv
            f32x2 alpha = one - w2 * e2;
            Mv[j] = alpha * Mv[j] + w2 * a2;
        }
        Rb[t * DVV] = rd2.x + rd2.y;
        wq[sl] = w_n; eaq[sl] = ea_n;
    }
}

// ---------------- Kernel 3: FC head + BCE + fused loss (last-block pattern) ----------------
__global__ __launch_bounds__(256) void k_fc(const float* __restrict__ Rr,
                                            const int* __restrict__ q_data,
                                            const float* __restrict__ q_embed_w,
                                            const float* __restrict__ read_w,
                                            const float* __restrict__ read_b,
                                            const float* __restrict__ pred_w,
                                            const float* __restrict__ pred_b,
                                            const float* __restrict__ target,
                                            float* __restrict__ out,
                                            float* __restrict__ acc) {
    __shared__ float Wl[64 * 196];   // 50.2 KB
    __shared__ float xl[64 * 100];   // 25.6 KB
    __shared__ float2 red[4];
    int tid = threadIdx.x;
    int r0 = blockIdx.x * 64;
    int fq = tid & 15;
    int rh = tid >> 4;   // 0..15

    for (int i = tid; i < 3072; i += 256) {
        int f = i / 48, p = i - f * 48;
        *(float4*)(Wl + f * 196 + p * 4) = *(const float4*)(read_w + f * 192 + p * 4);
    }

    float accv[4][4];
#pragma unroll
    for (int i = 0; i < 4; i++)
#pragma unroll
        for (int j = 0; j < 4; j++) accv[i][j] = 0.f;

    for (int kc = 0; kc < 2; kc++) {
        __syncthreads();
        for (int i = tid; i < 1536; i += 256) {
            int r = i / 24, p = i - r * 24;
            float4 val;
            if (kc == 0) {
                val = *(const float4*)(Rr + (long)(r0 + r) * DVV + p * 4);
            } else if (p < 8) {
                val = *(const float4*)(Rr + (long)(r0 + r) * DVV + 96 + p * 4);
            } else {
                int qi = q_data[r0 + r];
                val = *(const float4*)(q_embed_w + (long)qi * DKK + (p - 8) * 4);
            }
            *(float4*)(xl + r * 100 + p * 4) = val;
        }
        __syncthreads();
#pragma unroll 4
        for (int kk = 0; kk < 96; kk += 4) {
            float4 wv[4], x4[4];
#pragma unroll
            for (int i = 0; i < 4; i++)
                wv[i] = *(const float4*)(Wl + (fq + 16 * i) * 196 + kc * 96 + kk);
#pragma unroll
            for (int j = 0; j < 4; j++)
                x4[j] = *(const float4*)(xl + (rh * 4 + j) * 100 + kk);
#pragma unroll
            for (int i = 0; i < 4; i++)
#pragma unroll
                for (int j = 0; j < 4; j++) {
                    accv[i][j] = fmaf(x4[j].x, wv[i].x, accv[i][j]);
                    accv[i][j] = fmaf(x4[j].y, wv[i].y, accv[i][j]);
                    accv[i][j] = fmaf(x4[j].z, wv[i].z, accv[i][j]);
                    accv[i][j] = fmaf(x4[j].w, wv[i].w, accv[i][j]);
                }
        }
    }

    float pb = pred_b[0];
    float rb_[4], pw_[4];
#pragma unroll
    for (int i = 0; i < 4; i++) { rb_[i] = read_b[fq + 16 * i]; pw_[i] = pred_w[fq + 16 * i]; }

    float bce_sum = 0.f, cnt = 0.f;
#pragma unroll
    for (int j = 0; j < 4; j++) {
        float pv = 0.f;
#pragma unroll
        for (int i = 0; i < 4; i++)
            pv = fmaf(pw_[i], tanhf(accv[i][j] + rb_[i]), pv);
        pv += __shfl_xor(pv, 1, 64);
        pv += __shfl_xor(pv, 2, 64);
        pv += __shfl_xor(pv, 4, 64);
        pv += __shfl_xor(pv, 8, 64);
        if (fq == 0) {
            int row = r0 + rh * 4 + j;
            float tgt = target[row];
            float logit = pv + pb;
            float prob = 0.f;
            if (tgt >= 0.f) {
                prob = 1.f / (1.f + expf(-logit));
                float bce = fmaxf(logit, 0.f) - logit * tgt + log1pf(expf(-fabsf(logit)));
                bce_sum += bce;
                cnt += 1.f;
            }
            out[1 + row] = prob;
        }
    }
    bce_sum += __shfl_xor(bce_sum, 16, 64);
    bce_sum += __shfl_xor(bce_sum, 32, 64);
    cnt     += __shfl_xor(cnt, 16, 64);
    cnt     += __shfl_xor(cnt, 32, 64);
    int lane = tid & 63, wid = tid >> 6;
    if (lane == 0) { red[wid].x = bce_sum; red[wid].y = cnt; }
    __syncthreads();
    if (tid == 0) {
        float bsum = red[0].x + red[1].x + red[2].x + red[3].x;
        float csum = red[0].y + red[1].y + red[2].y + red[3].y;
        atomicAdd(&acc[0], bsum);
        atomicAdd(&acc[1], csum);
        __threadfence();
        unsigned prev = atomicAdd((unsigned*)acc + 2, 1u);
        if (prev == NFCB - 1) {          // last block computes the loss
            __threadfence();
            float B = atomicAdd(&acc[0], 0.f);
            float C = atomicAdd(&acc[1], 0.f);
            out[0] = B / fmaxf(C, 1.f);
        }
    }
}

extern "C" void kernel_launch(void* const* d_in, const int* in_sizes, int n_in,
                              void* d_out, int out_size, void* d_ws, size_t ws_size,
                              hipStream_t stream) {
    const int*   q_data     = (const int*)d_in[0];
    const int*   qa_data    = (const int*)d_in[1];
    const float* target     = (const float*)d_in[2];
    const float* q_embed_w  = (const float*)d_in[3];
    const float* qa_embed_w = (const float*)d_in[4];
    const float* mem_key    = (const float*)d_in[5];
    const float* init_mv    = (const float*)d_in[6];
    const float* erase_w    = (const float*)d_in[7];
    const float* erase_b    = (const float*)d_in[8];
    const float* add_w      = (const float*)d_in[9];
    const float* add_b      = (const float*)d_in[10];
    const float* read_w     = (const float*)d_in[11];
    const float* read_b     = (const float*)d_in[12];
    const float* pred_w     = (const float*)d_in[13];
    const float* pred_b     = (const float*)d_in[14];
    float* out = (float*)d_out;
    float* ws  = (float*)d_ws;

    float* w_all = ws + W_OFF;
    float* EA    = ws + EA_OFF;
    float* R     = ws + R_OFF;
    float* acc   = ws + ACC_OFF;

    k_pre<<<NSCB + NROW / 64, 256, 0, stream>>>(q_data, q_embed_w, mem_key,
                                                qa_data, qa_embed_w,
                                                erase_w, erase_b, add_w, add_b,
                                                w_all, EA, acc);
    k_scan<<<BB * 2, 512, 0, stream>>>(w_all, EA, init_mv, R);
    k_fc<<<NFCB, 256, 0, stream>>>(R, q_data, q_embed_w, read_w, read_b,
                                   pred_w, pred_b, target, out, acc);
}

// Round 14
// 187.653 us; speedup vs baseline: 1.0919x; 1.0919x over previous
//
#include <hip/hip_runtime.h>
#include <math.h>

#define BB 128
#define SS 200
#define MM 50
#define DKK 64
#define DVV 128
#define FF 64
#define NROW (BB*SS)   // 25600

#define WROW 64        // w padded layout: 64 floats/row, m<50 valid, rest zero
#define NFCB (NROW/64) // 400 k_fc blocks
#define WLDS 136       // k_pre/ea LDS bf16 row stride (2-way bank alias = free)
#define CLEN 25        // scan: steps per chunk (8 chunks x 25 = 200)
#define MP 25          // scan: m-pairs per thread (50 m as 25 float2)
#define NSCB 100       // scores blocks inside k_pre (256 items each)

// workspace layout (floats)
#define W_OFF   0L
#define EA_OFF  (W_OFF + (long)NROW*WROW)        // interleaved (e,a) float2
#define R_OFF   (EA_OFF + (long)NROW*DVV*2)
#define ACC_OFF (R_OFF + (long)NROW*DVV)         // [0]=bce [1]=cnt [2]=counter bits

typedef __attribute__((ext_vector_type(8))) short bf16x8;   // 8 bf16 (4 VGPRs)
typedef __attribute__((ext_vector_type(4))) float f32x4;
typedef __attribute__((ext_vector_type(2))) float f32x2;    // -> v_pk_*_f32

__device__ __forceinline__ float rlane(float v, int l) {
    return __builtin_bit_cast(float, __builtin_amdgcn_readlane(__builtin_bit_cast(unsigned, v), l));
}
__device__ __forceinline__ short f2bf(float f) {   // RNE fp32->bf16
    unsigned u = __builtin_bit_cast(unsigned, f);
    u += 0x7fff + ((u >> 16) & 1);
    return (short)(u >> 16);
}

// ---------------- Kernel 1: fused scores + ea (independent block types) ----------------
__global__ __launch_bounds__(256) void k_pre(const int* __restrict__ q_data,
                                             const float* __restrict__ q_embed_w,
                                             const float* __restrict__ mem_key,
                                             const int* __restrict__ qa_data,
                                             const float* __restrict__ qa_embed_w,
                                             const float* __restrict__ erase_w,
                                             const float* __restrict__ erase_b,
                                             const float* __restrict__ add_w,
                                             const float* __restrict__ add_b,
                                             float* __restrict__ w_out,
                                             float* __restrict__ EA,
                                             float* __restrict__ acc) {
    __shared__ union {
        short  wl[2 * 128 * WLDS];   // ea branch: bf16 weights, 69.6 KB
        float4 mk[MM * 16];          // scores branch: mem_key, 12.8 KB
    } sh;
    int tid = threadIdx.x;
    int bid = blockIdx.x;

    if (bid < NSCB) {
        // ---------- scores branch ----------
        if (bid == 0 && tid == 0) {
            acc[0] = 0.f; acc[1] = 0.f;
            ((unsigned*)acc)[2] = 0u;
        }
        const float4* mkg = (const float4*)mem_key;
        for (int i = tid; i < MM * 16; i += 256) sh.mk[i] = mkg[i];
        __syncthreads();

        int item = bid * 256 + tid;
        int qidx = q_data[item];
        const float4* qg = (const float4*)(q_embed_w + (long)qidx * DKK);
        float4 q[16];
#pragma unroll
        for (int i = 0; i < 16; i++) q[i] = qg[i];

        float s[MM];
        float mx = -1e30f;
#pragma unroll 2
        for (int m = 0; m < MM; m++) {
            float a = 0.f;
#pragma unroll
            for (int k4 = 0; k4 < 16; k4++) {
                float4 mkv = sh.mk[m * 16 + k4];
                float4 qv = q[k4];
                a = fmaf(qv.x, mkv.x, a);
                a = fmaf(qv.y, mkv.y, a);
                a = fmaf(qv.z, mkv.z, a);
                a = fmaf(qv.w, mkv.w, a);
            }
            s[m] = a;
            mx = fmaxf(mx, a);
        }
        float sum = 0.f;
#pragma unroll
        for (int m = 0; m < MM; m++) { s[m] = expf(s[m] - mx); sum += s[m]; }
        float inv = 1.f / sum;

        float* wo = w_out + (long)item * WROW;
#pragma unroll
        for (int m = 0; m < MM; m++) wo[m] = s[m] * inv;
#pragma unroll
        for (int m = MM; m < WROW; m++) wo[m] = 0.f;
        return;
    }

    // ---------- ea branch ----------
    int r0 = (bid - NSCB) * 64;
    int lane = tid & 63;
    int wv = tid >> 6;          // wave 0..3
    int n = lane & 15;
    int quad = lane >> 4;       // 0..3

    for (int i = tid; i < 8192; i += 256) {
        int mat = i >> 12;
        int r = (i >> 5) & 127;
        int p = i & 31;
        float4 src = *(const float4*)((mat ? add_w : erase_w) + r * 128 + p * 4);
        short4 d;
        d.x = f2bf(src.x); d.y = f2bf(src.y); d.z = f2bf(src.z); d.w = f2bf(src.w);
        *(short4*)(sh.wl + (mat * 128 + r) * WLDS + p * 4) = d;
    }

    int arow = r0 + wv * 16 + n;
    int qidx = qa_data[arow];
    const float* qp = qa_embed_w + (long)qidx * DVV + quad * 8;
    bf16x8 afrag[4];
#pragma unroll
    for (int kb = 0; kb < 4; kb++) {
        float4 lo = *(const float4*)(qp + kb * 32);
        float4 hi = *(const float4*)(qp + kb * 32 + 4);
        bf16x8 f;
        f[0] = f2bf(lo.x); f[1] = f2bf(lo.y); f[2] = f2bf(lo.z); f[3] = f2bf(lo.w);
        f[4] = f2bf(hi.x); f[5] = f2bf(hi.y); f[6] = f2bf(hi.z); f[7] = f2bf(hi.w);
        afrag[kb] = f;
    }

    float eb_[8], ab_[8];
#pragma unroll
    for (int vt = 0; vt < 8; vt++) {
        eb_[vt] = erase_b[vt * 16 + n];
        ab_[vt] = add_b[vt * 16 + n];
    }
    __syncthreads();

    int rowbase = r0 + wv * 16 + quad * 4;
#pragma unroll 2
    for (int vt = 0; vt < 8; vt++) {
        int vrow = vt * 16 + n;
        f32x4 ae = {0.f, 0.f, 0.f, 0.f};
        f32x4 aa = {0.f, 0.f, 0.f, 0.f};
#pragma unroll
        for (int kb = 0; kb < 4; kb++) {
            bf16x8 be = *(const bf16x8*)(sh.wl + vrow * WLDS + kb * 32 + quad * 8);
            bf16x8 ba = *(const bf16x8*)(sh.wl + (128 + vrow) * WLDS + kb * 32 + quad * 8);
            ae = __builtin_amdgcn_mfma_f32_16x16x32_bf16(afrag[kb], be, ae, 0, 0, 0);
            aa = __builtin_amdgcn_mfma_f32_16x16x32_bf16(afrag[kb], ba, aa, 0, 0, 0);
        }
        int v = vt * 16 + n;
        float eb = eb_[vt], ab = ab_[vt];
#pragma unroll
        for (int r = 0; r < 4; r++) {
            float ev = 1.f / (1.f + __expf(-(ae[r] + eb)));
            float av = 2.f / (1.f + __expf(-2.f * (aa[r] + ab))) - 1.f;
            float2 o; o.x = ev; o.y = av;
            *(float2*)(EA + (((long)(rowbase + r)) * DVV + v) * 2) = o;
        }
    }
}

// ---------------- Kernel 2: chunked affine scan — depth-2 STATIC double buffer ----------------
// Named register pairs (w0/ea0, w1/ea1), t-loop unrolled by 2 -> no dynamic array
// indexing, nothing demoted to LDS. Each load gets 2 steps of compute to land.
#define P1_STEP(WREG, EAREG)                                      \
    {                                                             \
        f32x2 e2 = {(EAREG).x, (EAREG).x};                        \
        f32x2 a2 = {(EAREG).y, (EAREG).y};                        \
        _Pragma("unroll")                                         \
        for (int j = 0; j < MP; j++) {                            \
            f32x2 w2 = {rlane(WREG, 2*j), rlane(WREG, 2*j+1)};    \
            f32x2 alpha = one - w2 * e2;                          \
            A2[j] = A2[j] * alpha;                                \
            B2[j] = alpha * B2[j] + w2 * a2;                      \
        }                                                         \
    }

#define P2_STEP(WREG, EAREG, TIDX)                                \
    {                                                             \
        f32x2 e2 = {(EAREG).x, (EAREG).x};                        \
        f32x2 a2 = {(EAREG).y, (EAREG).y};                        \
        f32x2 rd2 = {0.f, 0.f};                                   \
        _Pragma("unroll")                                         \
        for (int j = 0; j < MP; j++) {                            \
            f32x2 w2 = {rlane(WREG, 2*j), rlane(WREG, 2*j+1)};    \
            rd2 = rd2 + w2 * Mv[j];                               \
            f32x2 alpha = one - w2 * e2;                          \
            Mv[j] = alpha * Mv[j] + w2 * a2;                      \
        }                                                         \
        Rb[(TIDX) * DVV] = rd2.x + rd2.y;                         \
    }

__global__ __launch_bounds__(512, 2) void k_scan(const float* __restrict__ w_pad,
                                                 const float* __restrict__ EA,
                                                 const float* __restrict__ init_mv,
                                                 float* __restrict__ R) {
    __shared__ float Sb[MM * 64];      // 12.8 KB boundary state
    int b   = blockIdx.x >> 1;
    int vh  = blockIdx.x & 1;
    int tid = threadIdx.x;
    int lane  = tid & 63;
    int chunk = tid >> 6;              // wave id = chunk (0..7)
    int v  = vh * 64 + lane;
    int t0 = chunk * CLEN;

    const float* wbase = w_pad + ((long)b * SS + t0) * WROW;
    const float* eab   = EA + (((long)b * SS + t0) * DVV + v) * 2;
    float*       Rb    = R + ((long)b * SS + t0) * DVV + v;

    const f32x2 one = {1.f, 1.f};

    // ---- pass 1: compose the chunk's affine map per m-pair ----
    f32x2 A2[MP], B2[MP];
#pragma unroll
    for (int j = 0; j < MP; j++) { A2[j] = one; B2[j] = (f32x2){0.f, 0.f}; }

    float  w0 = wbase[lane];
    float2 ea0 = *(const float2*)eab;
    float  w1 = wbase[WROW + lane];
    float2 ea1 = *(const float2*)(eab + (long)DVV * 2);
#pragma unroll 1
    for (int t = 0; t < CLEN - 1; t += 2) {
        int tp = (t + 2 < CLEN) ? t + 2 : CLEN - 1;
        float  wn0  = wbase[tp * WROW + lane];
        float2 ean0 = *(const float2*)(eab + (long)tp * DVV * 2);
        P1_STEP(w0, ea0);
        w0 = wn0; ea0 = ean0;

        int tq = (t + 3 < CLEN) ? t + 3 : CLEN - 1;
        float  wn1  = wbase[tq * WROW + lane];
        float2 ean1 = *(const float2*)(eab + (long)tq * DVV * 2);
        P1_STEP(w1, ea1);
        w1 = wn1; ea1 = ean1;
    }
    P1_STEP(w0, ea0);   // tail: t = 24

    // ---- combine: sequential over chunks through LDS ----
    f32x2 Mv[MP];
    if (chunk == 0) {
#pragma unroll
        for (int j = 0; j < MP; j++) {
            Mv[j].x = init_mv[(2 * j) * DVV + v];
            Mv[j].y = init_mv[(2 * j + 1) * DVV + v];
        }
#pragma unroll
        for (int j = 0; j < MP; j++) {
            f32x2 nb = A2[j] * Mv[j] + B2[j];
            Sb[(2 * j) * 64 + lane] = nb.x;
            Sb[(2 * j + 1) * 64 + lane] = nb.y;
        }
    }
    __syncthreads();
    for (int c = 1; c < 8; c++) {
        if (chunk == c) {
#pragma unroll
            for (int j = 0; j < MP; j++) {
                Mv[j].x = Sb[(2 * j) * 64 + lane];
                Mv[j].y = Sb[(2 * j + 1) * 64 + lane];
            }
            if (c < 7) {
#pragma unroll
                for (int j = 0; j < MP; j++) {
                    f32x2 nb = A2[j] * Mv[j] + B2[j];
                    Sb[(2 * j) * 64 + lane] = nb.x;
                    Sb[(2 * j + 1) * 64 + lane] = nb.y;
                }
            }
        }
        __syncthreads();
    }

    // ---- pass 2: replay chunk, emitting reads (pre-update Mv) ----
    w0  = wbase[lane];
    ea0 = *(const float2*)eab;
    w1  = wbase[WROW + lane];
    ea1 = *(const float2*)(eab + (long)DVV * 2);
#pragma unroll 1
    for (int t = 0; t < CLEN - 1; t += 2) {
        int tp = (t + 2 < CLEN) ? t + 2 : CLEN - 1;
        float  wn0  = wbase[tp * WROW + lane];
        float2 ean0 = *(const float2*)(eab + (long)tp * DVV * 2);
        P2_STEP(w0, ea0, t);
        w0 = wn0; ea0 = ean0;

        int tq = (t + 3 < CLEN) ? t + 3 : CLEN - 1;
        float  wn1  = wbase[tq * WROW + lane];
        float2 ean1 = *(const float2*)(eab + (long)tq * DVV * 2);
        P2_STEP(w1, ea1, t + 1);
        w1 = wn1; ea1 = ean1;
    }
    P2_STEP(w0, ea0, CLEN - 1);   // tail: t = 24
}

// ---------------- Kernel 3: FC head + BCE + fused loss (last-block pattern) ----------------
__global__ __launch_bounds__(256) void k_fc(const float* __restrict__ Rr,
                                            const int* __restrict__ q_data,
                                            const float* __restrict__ q_embed_w,
                                            const float* __restrict__ read_w,
                                            const float* __restrict__ read_b,
                                            const float* __restrict__ pred_w,
                                            const float* __restrict__ pred_b,
                                            const float* __restrict__ target,
                                            float* __restrict__ out,
                                            float* __restrict__ acc) {
    __shared__ float Wl[64 * 196];   // 50.2 KB
    __shared__ float xl[64 * 100];   // 25.6 KB
    __shared__ float2 red[4];
    int tid = threadIdx.x;
    int r0 = blockIdx.x * 64;
    int fq = tid & 15;
    int rh = tid >> 4;   // 0..15

    for (int i = tid; i < 3072; i += 256) {
        int f = i / 48, p = i - f * 48;
        *(float4*)(Wl + f * 196 + p * 4) = *(const float4*)(read_w + f * 192 + p * 4);
    }

    float accv[4][4];
#pragma unroll
    for (int i = 0; i < 4; i++)
#pragma unroll
        for (int j = 0; j < 4; j++) accv[i][j] = 0.f;

    for (int kc = 0; kc < 2; kc++) {
        __syncthreads();
        for (int i = tid; i < 1536; i += 256) {
            int r = i / 24, p = i - r * 24;
            float4 val;
            if (kc == 0) {
                val = *(const float4*)(Rr + (long)(r0 + r) * DVV + p * 4);
            } else if (p < 8) {
                val = *(const float4*)(Rr + (long)(r0 + r) * DVV + 96 + p * 4);
            } else {
                int qi = q_data[r0 + r];
                val = *(const float4*)(q_embed_w + (long)qi * DKK + (p - 8) * 4);
            }
            *(float4*)(xl + r * 100 + p * 4) = val;
        }
        __syncthreads();
#pragma unroll 4
        for (int kk = 0; kk < 96; kk += 4) {
            float4 wv[4], x4[4];
#pragma unroll
            for (int i = 0; i < 4; i++)
                wv[i] = *(const float4*)(Wl + (fq + 16 * i) * 196 + kc * 96 + kk);
#pragma unroll
            for (int j = 0; j < 4; j++)
                x4[j] = *(const float4*)(xl + (rh * 4 + j) * 100 + kk);
#pragma unroll
            for (int i = 0; i < 4; i++)
#pragma unroll
                for (int j = 0; j < 4; j++) {
                    accv[i][j] = fmaf(x4[j].x, wv[i].x, accv[i][j]);
                    accv[i][j] = fmaf(x4[j].y, wv[i].y, accv[i][j]);
                    accv[i][j] = fmaf(x4[j].z, wv[i].z, accv[i][j]);
                    accv[i][j] = fmaf(x4[j].w, wv[i].w, accv[i][j]);
                }
        }
    }

    float pb = pred_b[0];
    float rb_[4], pw_[4];
#pragma unroll
    for (int i = 0; i < 4; i++) { rb_[i] = read_b[fq + 16 * i]; pw_[i] = pred_w[fq + 16 * i]; }

    float bce_sum = 0.f, cnt = 0.f;
#pragma unroll
    for (int j = 0; j < 4; j++) {
        float pv = 0.f;
#pragma unroll
        for (int i = 0; i < 4; i++)
            pv = fmaf(pw_[i], tanhf(accv[i][j] + rb_[i]), pv);
        pv += __shfl_xor(pv, 1, 64);
        pv += __shfl_xor(pv, 2, 64);
        pv += __shfl_xor(pv, 4, 64);
        pv += __shfl_xor(pv, 8, 64);
        if (fq == 0) {
            int row = r0 + rh * 4 + j;
            float tgt = target[row];
            float logit = pv + pb;
            float prob = 0.f;
            if (tgt >= 0.f) {
                prob = 1.f / (1.f + expf(-logit));
                float bce = fmaxf(logit, 0.f) - logit * tgt + log1pf(expf(-fabsf(logit)));
                bce_sum += bce;
                cnt += 1.f;
            }
            out[1 + row] = prob;
        }
    }
    bce_sum += __shfl_xor(bce_sum, 16, 64);
    bce_sum += __shfl_xor(bce_sum, 32, 64);
    cnt     += __shfl_xor(cnt, 16, 64);
    cnt     += __shfl_xor(cnt, 32, 64);
    int lane = tid & 63, wid = tid >> 6;
    if (lane == 0) { red[wid].x = bce_sum; red[wid].y = cnt; }
    __syncthreads();
    if (tid == 0) {
        float bsum = red[0].x + red[1].x + red[2].x + red[3].x;
        float csum = red[0].y + red[1].y + red[2].y + red[3].y;
        atomicAdd(&acc[0], bsum);
        atomicAdd(&acc[1], csum);
        __threadfence();
        unsigned prev = atomicAdd((unsigned*)acc + 2, 1u);
        if (prev == NFCB - 1) {          // last block computes the loss
            __threadfence();
            float B = atomicAdd(&acc[0], 0.f);
            float C = atomicAdd(&acc[1], 0.f);
            out[0] = B / fmaxf(C, 1.f);
        }
    }
}

extern "C" void kernel_launch(void* const* d_in, const int* in_sizes, int n_in,
                              void* d_out, int out_size, void* d_ws, size_t ws_size,
                              hipStream_t stream) {
    const int*   q_data     = (const int*)d_in[0];
    const int*   qa_data    = (const int*)d_in[1];
    const float* target     = (const float*)d_in[2];
    const float* q_embed_w  = (const float*)d_in[3];
    const float* qa_embed_w = (const float*)d_in[4];
    const float* mem_key    = (const float*)d_in[5];
    const float* init_mv    = (const float*)d_in[6];
    const float* erase_w    = (const float*)d_in[7];
    const float* erase_b    = (const float*)d_in[8];
    const float* add_w      = (const float*)d_in[9];
    const float* add_b      = (const float*)d_in[10];
    const float* read_w     = (const float*)d_in[11];
    const float* read_b     = (const float*)d_in[12];
    const float* pred_w     = (const float*)d_in[13];
    const float* pred_b     = (const float*)d_in[14];
    float* out = (float*)d_out;
    float* ws  = (float*)d_ws;

    float* w_all = ws + W_OFF;
    float* EA    = ws + EA_OFF;
    float* R     = ws + R_OFF;
    float* acc   = ws + ACC_OFF;

    k_pre<<<NSCB + NROW / 64, 256, 0, stream>>>(q_data, q_embed_w, mem_key,
                                                qa_data, qa_embed_w,
                                                erase_w, erase_b, add_w, add_b,
                                                w_all, EA, acc);
    k_scan<<<BB * 2, 512, 0, stream>>>(w_all, EA, init_mv, R);
    k_fc<<<NFCB, 256, 0, stream>>>(R, q_data, q_embed_w, read_w, read_b,
                                   pred_w, pred_b, target, out, acc);
}

// Round 15
// 182.456 us; speedup vs baseline: 1.1230x; 1.0285x over previous
//
#include <hip/hip_runtime.h>
#include <math.h>

#define BB 128
#define SS 200
#define MM 50
#define DKK 64
#define DVV 128
#define FF 64
#define NROW (BB*SS)   // 25600

#define WROW 64        // w padded layout: 64 floats/row, m<50 valid, rest zero
#define NFCB (NROW/64) // 400 k_fc blocks
#define WLDS 136       // k_pre/ea LDS bf16 row stride (2-way bank alias = free)
#define FLDS 200       // k_fc LDS bf16 read_w row stride (192+8)
#define CLEN 25        // scan: steps per chunk (8 chunks x 25 = 200)
#define MP 25          // scan: m-pairs per thread (50 m as 25 float2)
#define NSCB 100       // scores blocks inside k_pre (256 items each)

// workspace layout (floats)
#define W_OFF   0L
#define EA_OFF  (W_OFF + (long)NROW*WROW)        // interleaved (e,a) float2
#define R_OFF   (EA_OFF + (long)NROW*DVV*2)
#define ACC_OFF (R_OFF + (long)NROW*DVV)         // [0]=bce [1]=cnt [2]=counter bits

typedef __attribute__((ext_vector_type(8))) short bf16x8;   // 8 bf16 (4 VGPRs)
typedef __attribute__((ext_vector_type(4))) float f32x4;
typedef __attribute__((ext_vector_type(2))) float f32x2;    // -> v_pk_*_f32

__device__ __forceinline__ float rlane(float v, int l) {
    return __builtin_bit_cast(float, __builtin_amdgcn_readlane(__builtin_bit_cast(unsigned, v), l));
}
__device__ __forceinline__ short f2bf(float f) {   // RNE fp32->bf16
    unsigned u = __builtin_bit_cast(unsigned, f);
    u += 0x7fff + ((u >> 16) & 1);
    return (short)(u >> 16);
}
__device__ __forceinline__ bf16x8 cvt8(const float* p) {
    float4 lo = *(const float4*)p;
    float4 hi = *(const float4*)(p + 4);
    bf16x8 f;
    f[0] = f2bf(lo.x); f[1] = f2bf(lo.y); f[2] = f2bf(lo.z); f[3] = f2bf(lo.w);
    f[4] = f2bf(hi.x); f[5] = f2bf(hi.y); f[6] = f2bf(hi.z); f[7] = f2bf(hi.w);
    return f;
}

// ---------------- Kernel 1: fused scores + ea (independent block types) ----------------
__global__ __launch_bounds__(256) void k_pre(const int* __restrict__ q_data,
                                             const float* __restrict__ q_embed_w,
                                             const float* __restrict__ mem_key,
                                             const int* __restrict__ qa_data,
                                             const float* __restrict__ qa_embed_w,
                                             const float* __restrict__ erase_w,
                                             const float* __restrict__ erase_b,
                                             const float* __restrict__ add_w,
                                             const float* __restrict__ add_b,
                                             float* __restrict__ w_out,
                                             float* __restrict__ EA,
                                             float* __restrict__ acc) {
    __shared__ union {
        short  wl[2 * 128 * WLDS];   // ea branch: bf16 weights, 69.6 KB
        float4 mk[MM * 16];          // scores branch: mem_key, 12.8 KB
    } sh;
    int tid = threadIdx.x;
    int bid = blockIdx.x;

    if (bid < NSCB) {
        // ---------- scores branch ----------
        if (bid == 0 && tid == 0) {
            acc[0] = 0.f; acc[1] = 0.f;
            ((unsigned*)acc)[2] = 0u;
        }
        const float4* mkg = (const float4*)mem_key;
        for (int i = tid; i < MM * 16; i += 256) sh.mk[i] = mkg[i];
        __syncthreads();

        int item = bid * 256 + tid;
        int qidx = q_data[item];
        const float4* qg = (const float4*)(q_embed_w + (long)qidx * DKK);
        float4 q[16];
#pragma unroll
        for (int i = 0; i < 16; i++) q[i] = qg[i];

        float s[MM];
        float mx = -1e30f;
#pragma unroll 2
        for (int m = 0; m < MM; m++) {
            float a = 0.f;
#pragma unroll
            for (int k4 = 0; k4 < 16; k4++) {
                float4 mkv = sh.mk[m * 16 + k4];
                float4 qv = q[k4];
                a = fmaf(qv.x, mkv.x, a);
                a = fmaf(qv.y, mkv.y, a);
                a = fmaf(qv.z, mkv.z, a);
                a = fmaf(qv.w, mkv.w, a);
            }
            s[m] = a;
            mx = fmaxf(mx, a);
        }
        float sum = 0.f;
#pragma unroll
        for (int m = 0; m < MM; m++) { s[m] = expf(s[m] - mx); sum += s[m]; }
        float inv = 1.f / sum;

        float* wo = w_out + (long)item * WROW;
#pragma unroll
        for (int m = 0; m < MM; m++) wo[m] = s[m] * inv;
#pragma unroll
        for (int m = MM; m < WROW; m++) wo[m] = 0.f;
        return;
    }

    // ---------- ea branch ----------
    int r0 = (bid - NSCB) * 64;
    int lane = tid & 63;
    int wv = tid >> 6;          // wave 0..3
    int n = lane & 15;
    int quad = lane >> 4;       // 0..3

    for (int i = tid; i < 8192; i += 256) {
        int mat = i >> 12;
        int r = (i >> 5) & 127;
        int p = i & 31;
        float4 src = *(const float4*)((mat ? add_w : erase_w) + r * 128 + p * 4);
        short4 d;
        d.x = f2bf(src.x); d.y = f2bf(src.y); d.z = f2bf(src.z); d.w = f2bf(src.w);
        *(short4*)(sh.wl + (mat * 128 + r) * WLDS + p * 4) = d;
    }

    int arow = r0 + wv * 16 + n;
    int qidx = qa_data[arow];
    const float* qp = qa_embed_w + (long)qidx * DVV + quad * 8;
    bf16x8 afrag[4];
#pragma unroll
    for (int kb = 0; kb < 4; kb++) afrag[kb] = cvt8(qp + kb * 32);

    float eb_[8], ab_[8];
#pragma unroll
    for (int vt = 0; vt < 8; vt++) {
        eb_[vt] = erase_b[vt * 16 + n];
        ab_[vt] = add_b[vt * 16 + n];
    }
    __syncthreads();

    int rowbase = r0 + wv * 16 + quad * 4;
#pragma unroll 2
    for (int vt = 0; vt < 8; vt++) {
        int vrow = vt * 16 + n;
        f32x4 ae = {0.f, 0.f, 0.f, 0.f};
        f32x4 aa = {0.f, 0.f, 0.f, 0.f};
#pragma unroll
        for (int kb = 0; kb < 4; kb++) {
            bf16x8 be = *(const bf16x8*)(sh.wl + vrow * WLDS + kb * 32 + quad * 8);
            bf16x8 ba = *(const bf16x8*)(sh.wl + (128 + vrow) * WLDS + kb * 32 + quad * 8);
            ae = __builtin_amdgcn_mfma_f32_16x16x32_bf16(afrag[kb], be, ae, 0, 0, 0);
            aa = __builtin_amdgcn_mfma_f32_16x16x32_bf16(afrag[kb], ba, aa, 0, 0, 0);
        }
        int v = vt * 16 + n;
        float eb = eb_[vt], ab = ab_[vt];
#pragma unroll
        for (int r = 0; r < 4; r++) {
            float ev = 1.f / (1.f + __expf(-(ae[r] + eb)));
            float av = 2.f / (1.f + __expf(-2.f * (aa[r] + ab))) - 1.f;
            float2 o; o.x = ev; o.y = av;
            *(float2*)(EA + (((long)(rowbase + r)) * DVV + v) * 2) = o;
        }
    }
}

// ---------------- Kernel 2: chunked affine scan — depth-1, pk fp32 (proven 47.7 us) ----------------
__global__ __launch_bounds__(512, 2) void k_scan(const float* __restrict__ w_pad,
                                                 const float* __restrict__ EA,
                                                 const float* __restrict__ init_mv,
                                                 float* __restrict__ R) {
    __shared__ float Sb[MM * 64];      // 12.8 KB boundary state
    int b   = blockIdx.x >> 1;
    int vh  = blockIdx.x & 1;
    int tid = threadIdx.x;
    int lane  = tid & 63;
    int chunk = tid >> 6;              // wave id = chunk (0..7)
    int v  = vh * 64 + lane;
    int t0 = chunk * CLEN;

    const float* wbase = w_pad + ((long)b * SS + t0) * WROW;
    const float* eab   = EA + (((long)b * SS + t0) * DVV + v) * 2;
    float*       Rb    = R + ((long)b * SS + t0) * DVV + v;

    const f32x2 one = {1.f, 1.f};

    f32x2 A2[MP], B2[MP];
#pragma unroll
    for (int j = 0; j < MP; j++) { A2[j] = one; B2[j] = (f32x2){0.f, 0.f}; }

    float  w_cur  = wbase[lane];
    float2 ea_cur = *(const float2*)eab;
#pragma unroll 1
    for (int t = 0; t < CLEN; t++) {
        int tp = (t + 1 < CLEN) ? t + 1 : t;
        float  w_nxt  = wbase[tp * WROW + lane];
        float2 ea_nxt = *(const float2*)(eab + (long)tp * DVV * 2);
        f32x2 e2 = {ea_cur.x, ea_cur.x};
        f32x2 a2 = {ea_cur.y, ea_cur.y};
#pragma unroll
        for (int j = 0; j < MP; j++) {
            f32x2 w2 = {rlane(w_cur, 2 * j), rlane(w_cur, 2 * j + 1)};
            f32x2 alpha = one - w2 * e2;
            A2[j] = A2[j] * alpha;
            B2[j] = alpha * B2[j] + w2 * a2;
        }
        w_cur = w_nxt; ea_cur = ea_nxt;
    }

    f32x2 Mv[MP];
    if (chunk == 0) {
#pragma unroll
        for (int j = 0; j < MP; j++) {
            Mv[j].x = init_mv[(2 * j) * DVV + v];
            Mv[j].y = init_mv[(2 * j + 1) * DVV + v];
        }
#pragma unroll
        for (int j = 0; j < MP; j++) {
            f32x2 nb = A2[j] * Mv[j] + B2[j];
            Sb[(2 * j) * 64 + lane] = nb.x;
            Sb[(2 * j + 1) * 64 + lane] = nb.y;
        }
    }
    __syncthreads();
    for (int c = 1; c < 8; c++) {
        if (chunk == c) {
#pragma unroll
            for (int j = 0; j < MP; j++) {
                Mv[j].x = Sb[(2 * j) * 64 + lane];
                Mv[j].y = Sb[(2 * j + 1) * 64 + lane];
            }
            if (c < 7) {
#pragma unroll
                for (int j = 0; j < MP; j++) {
                    f32x2 nb = A2[j] * Mv[j] + B2[j];
                    Sb[(2 * j) * 64 + lane] = nb.x;
                    Sb[(2 * j + 1) * 64 + lane] = nb.y;
                }
            }
        }
        __syncthreads();
    }

    w_cur  = wbase[lane];
    ea_cur = *(const float2*)eab;
#pragma unroll 1
    for (int t = 0; t < CLEN; t++) {
        int tp = (t + 1 < CLEN) ? t + 1 : t;
        float  w_nxt  = wbase[tp * WROW + lane];
        float2 ea_nxt = *(const float2*)(eab + (long)tp * DVV * 2);
        f32x2 e2 = {ea_cur.x, ea_cur.x};
        f32x2 a2 = {ea_cur.y, ea_cur.y};
        f32x2 rd2 = {0.f, 0.f};
#pragma unroll
        for (int j = 0; j < MP; j++) {
            f32x2 w2 = {rlane(w_cur, 2 * j), rlane(w_cur, 2 * j + 1)};
            rd2 = rd2 + w2 * Mv[j];               // read uses PRE-update Mv
            f32x2 alpha = one - w2 * e2;
            Mv[j] = alpha * Mv[j] + w2 * a2;
        }
        Rb[t * DVV] = rd2.x + rd2.y;
        w_cur = w_nxt; ea_cur = ea_nxt;
    }
}

// ---------------- Kernel 3: FC head via bf16 MFMA + BCE + fused loss ----------------
// 64 rows x 64 f per block, 4 waves. K=192 ([R||q_e]). read_w staged bf16 in LDS
// (25.6 KB -> 6 blocks/CU). A-frags global->reg. D: col=f=lane&15, row=quad*4+reg.
__global__ __launch_bounds__(256) void k_fc(const float* __restrict__ Rr,
                                            const int* __restrict__ q_data,
                                            const float* __restrict__ q_embed_w,
                                            const float* __restrict__ read_w,
                                            const float* __restrict__ read_b,
                                            const float* __restrict__ pred_w,
                                            const float* __restrict__ pred_b,
                                            const float* __restrict__ target,
                                            float* __restrict__ out,
                                            float* __restrict__ acc) {
    __shared__ short Wl[64 * FLDS];   // 25.6 KB
    __shared__ float2 red[4];
    int tid = threadIdx.x;
    int r0 = blockIdx.x * 64;
    int lane = tid & 63;
    int wv = tid >> 6;          // wave 0..3
    int n = lane & 15;
    int quad = lane >> 4;       // 0..3

    // stage read_w -> bf16 LDS (64 f-rows x 48 float4)
    for (int i = tid; i < 3072; i += 256) {
        int f = i / 48, p = i - f * 48;
        float4 src = *(const float4*)(read_w + f * 192 + p * 4);
        short4 d;
        d.x = f2bf(src.x); d.y = f2bf(src.y); d.z = f2bf(src.z); d.w = f2bf(src.w);
        *(short4*)(Wl + f * FLDS + p * 4) = d;
    }

    // A-frags: row = r0 + wv*16 + n; k = kb*32 + quad*8 + j; kb 0..3 from R, 4..5 from q_e
    int arow = r0 + wv * 16 + n;
    const float* rp = Rr + (long)arow * DVV + quad * 8;
    int qi = q_data[arow];
    const float* qp = q_embed_w + (long)qi * DKK + quad * 8;
    bf16x8 afrag[6];
#pragma unroll
    for (int kb = 0; kb < 4; kb++) afrag[kb] = cvt8(rp + kb * 32);
#pragma unroll
    for (int kb = 0; kb < 2; kb++) afrag[4 + kb] = cvt8(qp + kb * 32);

    // per-lane epilogue constants for f = ft*16+n
    float rb_[4], pw_[4];
#pragma unroll
    for (int ft = 0; ft < 4; ft++) {
        rb_[ft] = read_b[ft * 16 + n];
        pw_[ft] = pred_w[ft * 16 + n];
    }
    float pb = pred_b[0];
    __syncthreads();

    int rowbase = r0 + wv * 16 + quad * 4;
    float pv[4] = {0.f, 0.f, 0.f, 0.f};   // pred-dot partials per row-reg
#pragma unroll
    for (int ft = 0; ft < 4; ft++) {
        int f = ft * 16 + n;               // B-frag: lane's column = read_w row
        f32x4 ac = {0.f, 0.f, 0.f, 0.f};
#pragma unroll
        for (int kb = 0; kb < 6; kb++) {
            bf16x8 bfr = *(const bf16x8*)(Wl + f * FLDS + kb * 32 + quad * 8);
            ac = __builtin_amdgcn_mfma_f32_16x16x32_bf16(afrag[kb], bfr, ac, 0, 0, 0);
        }
        float rb = rb_[ft], pw = pw_[ft];
#pragma unroll
        for (int r = 0; r < 4; r++) {
            float h = 2.f / (1.f + __expf(-2.f * (ac[r] + rb))) - 1.f;   // tanh
            pv[r] = fmaf(pw, h, pv[r]);
        }
    }

    float bce_sum = 0.f, cnt = 0.f;
#pragma unroll
    for (int r = 0; r < 4; r++) {
        float p = pv[r];
        p += __shfl_xor(p, 1, 64);
        p += __shfl_xor(p, 2, 64);
        p += __shfl_xor(p, 4, 64);
        p += __shfl_xor(p, 8, 64);
        if (n == 0) {
            int row = rowbase + r;
            float tgt = target[row];
            float logit = p + pb;
            float prob = 0.f;
            if (tgt >= 0.f) {
                prob = 1.f / (1.f + __expf(-logit));
                float bce = fmaxf(logit, 0.f) - logit * tgt + log1pf(__expf(-fabsf(logit)));
                bce_sum += bce;
                cnt += 1.f;
            }
            out[1 + row] = prob;
        }
    }
    // reduce over quads (values live on lanes 0,16,32,48)
    bce_sum += __shfl_xor(bce_sum, 16, 64);
    bce_sum += __shfl_xor(bce_sum, 32, 64);
    cnt     += __shfl_xor(cnt, 16, 64);
    cnt     += __shfl_xor(cnt, 32, 64);
    if (lane == 0) { red[wv].x = bce_sum; red[wv].y = cnt; }
    __syncthreads();
    if (tid == 0) {
        float bsum = red[0].x + red[1].x + red[2].x + red[3].x;
        float csum = red[0].y + red[1].y + red[2].y + red[3].y;
        atomicAdd(&acc[0], bsum);
        atomicAdd(&acc[1], csum);
        __threadfence();
        unsigned prev = atomicAdd((unsigned*)acc + 2, 1u);
        if (prev == NFCB - 1) {          // last block computes the loss
            __threadfence();
            float B = atomicAdd(&acc[0], 0.f);
            float C = atomicAdd(&acc[1], 0.f);
            out[0] = B / fmaxf(C, 1.f);
        }
    }
}

extern "C" void kernel_launch(void* const* d_in, const int* in_sizes, int n_in,
                              void* d_out, int out_size, void* d_ws, size_t ws_size,
                              hipStream_t stream) {
    const int*   q_data     = (const int*)d_in[0];
    const int*   qa_data    = (const int*)d_in[1];
    const float* target     = (const float*)d_in[2];
    const float* q_embed_w  = (const float*)d_in[3];
    const float* qa_embed_w = (const float*)d_in[4];
    const float* mem_key    = (const float*)d_in[5];
    const float* init_mv    = (const float*)d_in[6];
    const float* erase_w    = (const float*)d_in[7];
    const float* erase_b    = (const float*)d_in[8];
    const float* add_w      = (const float*)d_in[9];
    const float* add_b      = (const float*)d_in[10];
    const float* read_w     = (const float*)d_in[11];
    const float* read_b     = (const float*)d_in[12];
    const float* pred_w     = (const float*)d_in[13];
    const float* pred_b     = (const float*)d_in[14];
    float* out = (float*)d_out;
    float* ws  = (float*)d_ws;

    float* w_all = ws + W_OFF;
    float* EA    = ws + EA_OFF;
    float* R     = ws + R_OFF;
    float* acc   = ws + ACC_OFF;

    k_pre<<<NSCB + NROW / 64, 256, 0, stream>>>(q_data, q_embed_w, mem_key,
                                                qa_data, qa_embed_w,
                                                erase_w, erase_b, add_w, add_b,
                                                w_all, EA, acc);
    k_scan<<<BB * 2, 512, 0, stream>>>(w_all, EA, init_mv, R);
    k_fc<<<NFCB, 256, 0, stream>>>(R, q_data, q_embed_w, read_w, read_b,
                                   pred_w, pred_b, target, out, acc);
}